// Round 4
// baseline (967.099 us; speedup 1.0000x reference)
//
#include <hip/hip_runtime.h>
#include <hip/hip_bf16.h>

// Problem constants (fixed by reference):
// N=400000, H=256, C=128, A=32, G=512, NG=1024, BN_EPS=1e-5
#define NNODES 400000
#define BM 16            // nodes per block in K1 (400000/16 = 25000 exact)

typedef __attribute__((ext_vector_type(8))) short  short8;   // 8 x bf16 (4 VGPRs)
typedef __attribute__((ext_vector_type(4))) float  floatx4;  // 4 x f32 acc

typedef unsigned short u16;
typedef unsigned int   u32;

// fp32 -> bf16 round-to-nearest-even (inputs are finite gaussians; no NaN path)
__device__ __forceinline__ u16 f2bf(float f) {
    u32 u = __builtin_bit_cast(u32, f);
    u += 0x7fffu + ((u >> 16) & 1u);
    return (u16)(u >> 16);
}

// ---------------------------------------------------------------------------
// K0: build packed bf16 weights, zero-free two-section layout.
//   Gate section (64K u16):  idx = kc*4096 + quad*1024 + col*8 + j
//                            value = Wg[kc*32+quad*8+j][col],  kc 0..15
//   T section    (32K u16):  idx = 65536 + kct*4096 + quad*1024 + col*8 + j
//                            value = Wt[kct*32+quad*8+j][col], kct 0..7
// 16B contiguous per (tile,quad,col) -> dwordx4 B-fragment loads in K1.
// ---------------------------------------------------------------------------
__global__ __launch_bounds__(256) void k0_build(
    const float* __restrict__ Wg, const float* __restrict__ Wt,
    u16* __restrict__ Bp)
{
    int base = (blockIdx.x * 256 + threadIdx.x) * 4;   // 96 blocks -> 98304
    #pragma unroll
    for (int e = 0; e < 4; e++) {
        int idx   = base + e;
        int local = idx & 4095;
        int quad  = local >> 10;
        int col   = (local >> 3) & 127;
        int j     = local & 7;
        float v;
        if (idx < 65536) {
            int kc = idx >> 12;
            v = Wg[(kc * 32 + quad * 8 + j) * 128 + col];
        } else {
            int kct = (idx - 65536) >> 12;
            v = Wt[(kct * 32 + quad * 8 + j) * 128 + col];
        }
        Bp[idx] = f2bf(v);
    }
}

// ---------------------------------------------------------------------------
// K1 (round 4): MAX-OCCUPANCY structure — 32 waves/CU.
// Diagnosis history: rounds 0/2/3 (three different stall structures) all land
// 285-375us with the one invariant being 16 waves/CU (88 unified regs, 32KB
// LDS). FETCH_SIZE ~= half the mandatory 819MB (L3 retains ~50% across graph
// replays) -> true HBM rate ~1.4TB/s, NOT BW-bound. VALU 27 + MFMA 11 ->
// ~60% latency stall. Lever: the 64-reg occupancy cliff (<=64 -> 32 waves/CU).
// Structure:
//   - BM=16 nodes/block, 256 thr / 4 waves; wave w = col-quarter: 16 nodes x
//     32 cols (gate+t) -> accumulator = 16 f32 (irreducible floor).
//   - A staged as BF16 in LDS (8KB/block): reg-stage (load f32 row -> f2bf
//     pack -> ds_write_b64). Kills the in-loop f2bf + float4 pressure; inner
//     loop = 1 ds_read_b128 + 2-4 B loads + 2-4 MFMA.
//   - XOR swizzle at 16B units: row r's unit u stored at u^(r&7); read at
//     (kc*4+quad)^(l15&7). Write side = same involution (both-sides rule).
//     Read banks: 8 distinct units x 4 banks = 32, 2-way (free).
//   - B per-lane from Bp (192KB L2-resident), same layout as before.
//   - 3 barriers/block (publish init / WAR / publish fin).
//   - __launch_bounds__(256, 8) FORCES <=64 unified regs -> 8 blocks/CU =
//     32 waves/CU. Tripwire: if WRITE_SIZE explodes, allocator spilled ->
//     relax to (256,6).
// ---------------------------------------------------------------------------
__global__ __launch_bounds__(256, 8) void k1_gemm(
    const float* __restrict__ initS, const float* __restrict__ finS,
    const int* __restrict__ gids, const u16* __restrict__ Bp,
    const float* __restrict__ bg, const float* __restrict__ bt,
    float* __restrict__ readout)
{
    __shared__ __align__(16) u16 Abuf[BM * 256];   // 8 KB bf16 A tile

    const int tid  = threadIdx.x;
    const int w    = tid >> 6;        // wave 0..3 = col-quarter
    const int lane = tid & 63;
    const int quad = lane >> 4;       // 0..3
    const int l15  = lane & 15;       // 0..15
    const int nodeBase = blockIdx.x * BM;

    const int myg = gids[nodeBase + l15];   // gid of block row l15

    // ---- stage: wave w loads rows w*4..w*4+4 (f32), packs bf16, swizzled ds_write
    auto stage = [&](const float* mat) {
        const float* s = mat + (size_t)(nodeBase + w * 4) * 256 + lane * 4;
        float4 v0 = *reinterpret_cast<const float4*>(s);
        float4 v1 = *reinterpret_cast<const float4*>(s + 256);
        float4 v2 = *reinterpret_cast<const float4*>(s + 512);
        float4 v3 = *reinterpret_cast<const float4*>(s + 768);
        const int u    = lane >> 1;          // 16B unit index 0..31
        const int half = (lane & 1) << 2;    // u16 offset within unit
        auto put = [&](int r, float4 v) {
            uint2 p;
            p.x = ((u32)f2bf(v.y) << 16) | f2bf(v.x);
            p.y = ((u32)f2bf(v.w) << 16) | f2bf(v.z);
            *reinterpret_cast<uint2*>(Abuf + r * 256 + ((u ^ (r & 7)) << 3) + half) = p;
        };
        put(w * 4 + 0, v0);
        put(w * 4 + 1, v1);
        put(w * 4 + 2, v2);
        put(w * 4 + 3, v3);
    };

    floatx4 accg[2], acct[2];
    #pragma unroll
    for (int i = 0; i < 2; i++) {
        accg[i] = (floatx4){0.f, 0.f, 0.f, 0.f};
        acct[i] = (floatx4){0.f, 0.f, 0.f, 0.f};
    }

    // lane-fixed B base for this wave's 32 cols (u16 elements)
    const u16* BL = Bp + quad * 1024 + (w * 32 + l15) * 8;
    const int m8 = l15 & 7;   // read-side swizzle mask (== row&7 for row l15)

    stage(initS);
    __syncthreads();   // publish A(init)

    // ---- phase 1: gate += init @ Wg[0:256], kc 0..7, 2 MFMA/iter ----
    #pragma unroll 2
    for (int kc = 0; kc < 8; kc++) {
        short8 af = *reinterpret_cast<const short8*>(
            Abuf + l15 * 256 + (((kc * 4 + quad) ^ m8) << 3));
        const u16* bp = BL + (size_t)kc * 4096;
        short8 b0 = *reinterpret_cast<const short8*>(bp);
        short8 b1 = *reinterpret_cast<const short8*>(bp + 128);
        accg[0] = __builtin_amdgcn_mfma_f32_16x16x32_bf16(af, b0, accg[0], 0, 0, 0);
        accg[1] = __builtin_amdgcn_mfma_f32_16x16x32_bf16(af, b1, accg[1], 0, 0, 0);
    }

    __syncthreads();   // WAR: phase-1 A reads done before overwrite
    stage(finS);
    __syncthreads();   // publish A(fin)

    // ---- phase 2: gate += fin @ Wg[256:512]; t = fin @ Wt. 4 MFMA/iter ----
    #pragma unroll 1
    for (int kc = 0; kc < 8; kc++) {
        short8 af = *reinterpret_cast<const short8*>(
            Abuf + l15 * 256 + (((kc * 4 + quad) ^ m8) << 3));
        const u16* bpg = BL + (size_t)(kc + 8) * 4096;
        const u16* bpt = BL + 65536 + (size_t)kc * 4096;
        short8 g0 = *reinterpret_cast<const short8*>(bpg);
        short8 g1 = *reinterpret_cast<const short8*>(bpg + 128);
        short8 t0 = *reinterpret_cast<const short8*>(bpt);
        short8 t1 = *reinterpret_cast<const short8*>(bpt + 128);
        accg[0] = __builtin_amdgcn_mfma_f32_16x16x32_bf16(af, g0, accg[0], 0, 0, 0);
        accg[1] = __builtin_amdgcn_mfma_f32_16x16x32_bf16(af, g1, accg[1], 0, 0, 0);
        acct[0] = __builtin_amdgcn_mfma_f32_16x16x32_bf16(af, t0, acct[0], 0, 0, 0);
        acct[1] = __builtin_amdgcn_mfma_f32_16x16x32_bf16(af, t1, acct[1], 0, 0, 0);
    }

    // ---- epilogue: fuse + segment-sum from registers ----
    // C/D layout: col = w*32 + ct*16 + l15, row (block-local) = quad*4 + i.
    const int gFirst = __shfl(myg, 0);    // lane 0 holds row 0
    const int gLast  = __shfl(myg, 15);   // lane 15 holds row 15
    const int colBase = w * 32;

    if (gFirst == gLast) {
        // fast path: whole 16-row block tile in one graph
        #pragma unroll
        for (int ct = 0; ct < 2; ct++) {
            const int col = colBase + ct * 16 + l15;
            const float bgv = bg[col];
            const float btv = bt[col];
            float s = 0.f;
            #pragma unroll
            for (int i = 0; i < 4; i++) {
                float g = accg[ct][i] + bgv;
                float t = acct[ct][i] + btv;
                s += t / (1.0f + __expf(-g));
            }
            s += __shfl_xor(s, 16);   // sum across quads (rows)
            s += __shfl_xor(s, 32);
            if (quad == ct)           // 1 atomic instr per ct per wave
                atomicAdd(&readout[gFirst * 128 + col], s);
        }
    } else {
        // slow path (~4% of blocks): per-lane sorted-run flush over its 4 rows
        float s[2] = {0.f, 0.f};
        int curg = __shfl(myg, quad * 4);
        #pragma unroll
        for (int i = 0; i < 4; i++) {
            int g = __shfl(myg, quad * 4 + i);
            if (g != curg) {
                #pragma unroll
                for (int ct = 0; ct < 2; ct++) {
                    atomicAdd(&readout[curg * 128 + colBase + ct * 16 + l15], s[ct]);
                    s[ct] = 0.f;
                }
                curg = g;
            }
            #pragma unroll
            for (int ct = 0; ct < 2; ct++) {
                float gg = accg[ct][i] + bg[colBase + ct * 16 + l15];
                float tt = acct[ct][i] + bt[colBase + ct * 16 + l15];
                s[ct] += tt / (1.0f + __expf(-gg));
            }
        }
        #pragma unroll
        for (int ct = 0; ct < 2; ct++)
            atomicAdd(&readout[curg * 128 + colBase + ct * 16 + l15], s[ct]);
    }
}

// ---------------------------------------------------------------------------
// K2: BatchNorm column stats over the 1024-row batch (biased variance),
// folded into scale/shift: y = x*scale[c] + shift[c].
// ---------------------------------------------------------------------------
__global__ __launch_bounds__(256) void k2_stats(
    const float* __restrict__ readout, const float* __restrict__ aux,
    const float* __restrict__ gamma, const float* __restrict__ beta,
    float* __restrict__ scale, float* __restrict__ shift)
{
    const int col = blockIdx.x;     // 0..159
    const int tid = threadIdx.x;
    float s = 0.f, q = 0.f;
    for (int g = tid; g < 1024; g += 256) {
        float v = (col < 128) ? readout[g * 128 + col] : aux[g * 32 + (col - 128)];
        s += v; q += v * v;
    }
    #pragma unroll
    for (int off = 32; off > 0; off >>= 1) {
        s += __shfl_down(s, off);
        q += __shfl_down(q, off);
    }
    __shared__ float ps[4], pq[4];
    if ((tid & 63) == 0) { ps[tid >> 6] = s; pq[tid >> 6] = q; }
    __syncthreads();
    if (tid == 0) {
        float S = ps[0] + ps[1] + ps[2] + ps[3];
        float Q = pq[0] + pq[1] + pq[2] + pq[3];
        float mean = S * (1.0f / 1024.0f);
        float var  = Q * (1.0f / 1024.0f) - mean * mean;
        float rstd = rsqrtf(var + 1e-5f);
        float sc   = gamma[col] * rstd;
        scale[col] = sc;
        shift[col] = beta[col] - mean * sc;
    }
}

// ---------------------------------------------------------------------------
// K3a: hidden = relu(norm @ W1 + b1), BN fold applied inside the k-loop so the
// activations are RAW global rows (wave-uniform addresses -> scalar loads).
// ---------------------------------------------------------------------------
__global__ __launch_bounds__(256) void k3a_hidden(
    const float* __restrict__ readout, const float* __restrict__ aux,
    const float* __restrict__ scale, const float* __restrict__ shift,
    const float* __restrict__ W1, const float* __restrict__ b1,
    float* __restrict__ hidden)
{
    const int g0  = blockIdx.x * 4;   // 256 blocks
    const int tid = threadIdx.x;
    const float* r0 = readout + (size_t)g0 * 128;
    const float* a0 = aux     + (size_t)g0 * 32;

    #pragma unroll
    for (int jj = 0; jj < 2; jj++) {
        const int j = tid + jj * 256;
        float acc0 = 0.f, acc1 = 0.f, acc2 = 0.f, acc3 = 0.f, accS = 0.f;
        for (int k = 0; k < 128; k++) {
            float wv = W1[k * 512 + j];
            accS += shift[k] * wv;
            float wsv = scale[k] * wv;
            acc0 += r0[k]       * wsv;
            acc1 += r0[128 + k] * wsv;
            acc2 += r0[256 + k] * wsv;
            acc3 += r0[384 + k] * wsv;
        }
        for (int k = 0; k < 32; k++) {
            float wv = W1[(128 + k) * 512 + j];
            accS += shift[128 + k] * wv;
            float wsv = scale[128 + k] * wv;
            acc0 += a0[k]      * wsv;
            acc1 += a0[32 + k] * wsv;
            acc2 += a0[64 + k] * wsv;
            acc3 += a0[96 + k] * wsv;
        }
        float bb = b1[j] + accS;
        hidden[(size_t)(g0 + 0) * 512 + j] = fmaxf(acc0 + bb, 0.f);
        hidden[(size_t)(g0 + 1) * 512 + j] = fmaxf(acc1 + bb, 0.f);
        hidden[(size_t)(g0 + 2) * 512 + j] = fmaxf(acc2 + bb, 0.f);
        hidden[(size_t)(g0 + 3) * 512 + j] = fmaxf(acc3 + bb, 0.f);
    }
}

// ---------------------------------------------------------------------------
// K3b: logits = hidden @ W2 + b2. Same uniform-broadcast trick on hidden rows.
// ---------------------------------------------------------------------------
__global__ __launch_bounds__(256) void k3b_logits(
    const float* __restrict__ hidden, const float* __restrict__ W2,
    const float* __restrict__ b2, float* __restrict__ out)
{
    const int g0  = blockIdx.x * 4;   // 256 blocks
    const int tid = threadIdx.x;
    const int j   = tid & 127;
    const int rh  = tid >> 7;         // rows rh*2, rh*2+1
    const float* h0 = hidden + (size_t)(g0 + rh * 2) * 512;
    float acc0 = 0.f, acc1 = 0.f;
    for (int k = 0; k < 512; k++) {
        float wv = W2[k * 128 + j];
        acc0 += h0[k]       * wv;
        acc1 += h0[512 + k] * wv;
    }
    float bb = b2[j];
    out[(size_t)(g0 + rh * 2 + 0) * 128 + j] = acc0 + bb;
    out[(size_t)(g0 + rh * 2 + 1) * 128 + j] = acc1 + bb;
}

// ---------------------------------------------------------------------------
extern "C" void kernel_launch(void* const* d_in, const int* in_sizes, int n_in,
                              void* d_out, int out_size, void* d_ws, size_t ws_size,
                              hipStream_t stream)
{
    const float* initS = (const float*)d_in[0];   // [400000,256]
    const float* finS  = (const float*)d_in[1];   // [400000,256]
    const float* aux   = (const float*)d_in[2];   // [1024,32]
    const int*   gid   = (const int*)d_in[3];     // [400000] sorted
    // d_in[4] = num_graphs scalar (1024), unused
    const float* Wg    = (const float*)d_in[5];   // [512,128]
    const float* bg    = (const float*)d_in[6];   // [128]
    const float* Wt    = (const float*)d_in[7];   // [256,128]
    const float* bt    = (const float*)d_in[8];   // [128]
    const float* gamma = (const float*)d_in[9];   // [160]
    const float* beta  = (const float*)d_in[10];  // [160]
    const float* W1    = (const float*)d_in[11];  // [160,512]
    const float* b1    = (const float*)d_in[12];  // [512]
    const float* W2    = (const float*)d_in[13];  // [512,128]
    const float* b2    = (const float*)d_in[14];  // [128]
    float* out = (float*)d_out;                   // [1024,128]

    char* ws = (char*)d_ws;
    u16*   Bp      = (u16*)(ws + 0);              // 192 KB packed bf16 weights
    float* readout = (float*)(ws + 262144);       // 512 KB  [1024,128]
    float* scale   = (float*)(ws + 786432);       // 640 B
    float* shift   = (float*)(ws + 787456);       // 640 B
    float* hidden  = (float*)(ws + 1048576);      // 2 MB    [1024,512]

    k0_build  <<<96, 256, 0, stream>>>(Wg, Wt, Bp);
    hipMemsetAsync(readout, 0, 1024 * 128 * sizeof(float), stream);
    k1_gemm   <<<NNODES / BM, 256, 0, stream>>>(initS, finS, gid, Bp, bg, bt, readout);
    k2_stats  <<<160, 256, 0, stream>>>(readout, aux, gamma, beta, scale, shift);
    k3a_hidden<<<256, 256, 0, stream>>>(readout, aux, scale, shift, W1, b1, hidden);
    k3b_logits<<<256, 256, 0, stream>>>(hidden, W2, b2, out);
}